// Round 12
// baseline (386.429 us; speedup 1.0000x reference)
//
#include <hip/hip_runtime.h>
#include <math.h>

// NanoRAG: cosine-sim retrieval + top-8 + softmax fusion.
// K0 qprep: normalize queries -> qn fp32 + A-fragment bf16 (R11-proven)
// K1 score: fused linear-stream hi-only MFMA + per-block top-8 (R11-proven)
// K2 cand: 1024 blocks (q,chunk): merge 128 sorted lists -> top-16/chunk
// K3 rescore: 512 blocks: exact fp32 rescore of 256 candidates/query
// K4 final: top-8 of rescored, softmax, gather+fuse -> d_out
// K5 PROBE: max-BW linear read of docs (fill/m13 idiom) — rocprof readout
//           decides: platform read ceiling vs kernel structure flaw.
//
// d_out layout (fp32): fused[64*384], scores[64*8], idx[64*8]

#define EMBED 384
#define NDOCS 262144
#define BATCH 64
#define TOPK 8
#define NBLK 2048
#define EPSN 1e-8f

typedef __attribute__((ext_vector_type(8))) short bf16x8;
typedef __attribute__((ext_vector_type(4))) float f32x4;

#define INS8(s_, i_) do {                                                     \
    if ((s_) > ts[7] || ((s_) == ts[7] && (i_) < ti[7])) {                    \
        ts[7] = (s_); ti[7] = (i_);                                           \
        _Pragma("unroll")                                                     \
        for (int r_ = 7; r_ > 0; --r_) {                                      \
            bool sw_ = (ts[r_] > ts[r_-1]) ||                                 \
                       (ts[r_] == ts[r_-1] && ti[r_] < ti[r_-1]);             \
            float a_ = ts[r_-1]; int b_ = ti[r_-1];                           \
            ts[r_-1] = sw_ ? ts[r_] : a_;  ti[r_-1] = sw_ ? ti[r_] : b_;      \
            ts[r_]   = sw_ ? a_ : ts[r_];  ti[r_]   = sw_ ? b_ : ti[r_];      \
        }                                                                     \
    }                                                                         \
} while (0)

#define INS16(s_, i_) do {                                                    \
    if ((s_) > ts[15] || ((s_) == ts[15] && (i_) < ti[15])) {                 \
        ts[15] = (s_); ti[15] = (i_);                                         \
        _Pragma("unroll")                                                     \
        for (int r_ = 15; r_ > 0; --r_) {                                     \
            bool sw_ = (ts[r_] > ts[r_-1]) ||                                 \
                       (ts[r_] == ts[r_-1] && ti[r_] < ti[r_-1]);             \
            float a_ = ts[r_-1]; int b_ = ti[r_-1];                           \
            ts[r_-1] = sw_ ? ts[r_] : a_;  ti[r_-1] = sw_ ? ti[r_] : b_;      \
            ts[r_]   = sw_ ? a_ : ts[r_];  ti[r_]   = sw_ ? b_ : ti[r_];      \
        }                                                                     \
    }                                                                         \
} while (0)

__device__ __forceinline__ unsigned rne1(float f) {
    unsigned u = __float_as_uint(f);
    return (u + 0x7fffu + ((u >> 16) & 1u)) >> 16;
}

template<int OFF>
__device__ __forceinline__ int4 gload_s(unsigned voff, const void* sbase) {
    int4 r;
    asm volatile("global_load_dwordx4 %0, %1, %2 offset:%3"
                 : "=v"(r) : "v"(voff), "s"(sbase), "i"(OFF) : "memory");
    return r;
}

// ---------------- K0: query prep (R10/R11-proven) ----------------
__global__ void qprep_kernel(const float* __restrict__ q,
                             float* __restrict__ qn,
                             unsigned short* __restrict__ qhf) {
    const int row = blockIdx.x;
    const int lane = threadIdx.x;
    float v[6];
    float s = 0.f;
#pragma unroll
    for (int i = 0; i < 6; ++i) {
        v[i] = q[row * EMBED + lane + 64 * i];
        s = fmaf(v[i], v[i], s);
    }
#pragma unroll
    for (int off = 32; off > 0; off >>= 1) s += __shfl_xor(s, off);
    float rinv = 1.0f / (sqrtf(s) + EPSN);
#pragma unroll
    for (int i = 0; i < 6; ++i) {
        int k = lane + 64 * i;
        float f = v[i] * rinv;
        qn[row * EMBED + k] = f;
        qhf[(row >> 4) * 6144 + (k >> 5) * 512 + ((k >> 3) & 3) * 128
            + (row & 15) * 8 + (k & 7)] = (unsigned short)rne1(f);
    }
}

// ---------------- K1: fused linear-stream score + top-8 (R11-proven) ------
__global__ __launch_bounds__(256, 3) void score_topk_kernel(
        const float* __restrict__ docs,
        const unsigned short* __restrict__ qhf,
        float* __restrict__ pscore, int* __restrict__ pidx) {
    __shared__ __align__(16) char smem[33168];
    float* S  = (float*)(smem + 24576);
    float* RN = (float*)(smem + 33024);

    const int tid = threadIdx.x;
    const int l = tid & 63;
    const int w = tid >> 6;
    const int lb15 = l & 15;
    const int d0 = blockIdx.x * 128;

    int4 qreg[12];
    {
        const unsigned qvb = (unsigned)(w * 12288 + l * 16);
#pragma unroll
        for (int kb = 0; kb < 12; ++kb)
            qreg[kb] = gload_s<0>(qvb + kb * 1024u, qhf);
    }

    const unsigned vb = (unsigned)d0 * 1536u + (unsigned)(tid * 16);
    int4 rawA[6], rawB[6];
#pragma unroll
    for (int i = 0; i < 6; ++i) rawA[i] = gload_s<0>(vb + i * 4096u, docs);
#pragma unroll
    for (int i = 0; i < 6; ++i) rawB[i] = gload_s<0>(vb + (i + 6) * 4096u, docs);

    uint2 sh[12];
    unsigned dsw[12];
    float ts[8]; int ti[8];
#pragma unroll
    for (int r = 0; r < 8; ++r) { ts[r] = -3.402823466e38f; ti[r] = 0x7fffffff; }

    const unsigned abase = (unsigned)(lb15 * 768);
    const unsigned key = (unsigned)((l & 7) << 4);
    const unsigned kq16 = (unsigned)((l >> 4) * 16);
    const int sq_ = tid & 63;

#define CONV(i, R, ri) {                                                       \
    int F = tid + (i) * 256;                                                   \
    float f0 = __int_as_float(R[ri].x), f1 = __int_as_float(R[ri].y);          \
    float f2 = __int_as_float(R[ri].z), f3 = __int_as_float(R[ri].w);          \
    sh[i].x = rne1(f0) | (rne1(f1) << 16);                                     \
    sh[i].y = rne1(f2) | (rne1(f3) << 16);                                     \
    int dd = (F * 10923) >> 20;                                                \
    int r4 = F - dd * 96;                                                      \
    dsw[i] = (unsigned)(dd * 768) + (((unsigned)(r4 * 8)) ^ ((unsigned)((dd & 7) << 4))); \
}

#define KITER(J, LAST) {                                                       \
    asm volatile("s_waitcnt vmcnt(6)" ::: "memory");                           \
    __builtin_amdgcn_sched_barrier(0);                                         \
    _Pragma("unroll")                                                          \
    for (int i = 0; i < 6; ++i) CONV(i, rawA, i);                              \
    if (!(LAST)) {                                                             \
        _Pragma("unroll")                                                      \
        for (int i = 0; i < 6; ++i)                                            \
            rawA[i] = gload_s<0>(vb + ((J) + 1) * 49152u + i * 4096u, docs);   \
    }                                                                          \
    asm volatile("s_waitcnt vmcnt(%0)" :: "i"((LAST) ? 0 : 6) : "memory");     \
    __builtin_amdgcn_sched_barrier(0);                                         \
    _Pragma("unroll")                                                          \
    for (int i = 6; i < 12; ++i) CONV(i, rawB, i - 6);                         \
    if (!(LAST)) {                                                             \
        _Pragma("unroll")                                                      \
        for (int i = 0; i < 6; ++i)                                            \
            rawB[i] = gload_s<0>(vb + ((J) + 1) * 49152u + (i + 6) * 4096u, docs); \
    }                                                                          \
    asm volatile("s_waitcnt lgkmcnt(0)" ::: "memory");                         \
    __builtin_amdgcn_s_barrier();                                              \
    _Pragma("unroll")                                                          \
    for (int i = 0; i < 12; ++i) *(uint2*)(smem + dsw[i]) = sh[i];             \
    asm volatile("s_waitcnt lgkmcnt(0)" ::: "memory");                         \
    __builtin_amdgcn_s_barrier();                                              \
    f32x4 acc0 = (f32x4){0.f,0.f,0.f,0.f}, acc1 = (f32x4){0.f,0.f,0.f,0.f};   \
    f32x4 nrm0 = (f32x4){0.f,0.f,0.f,0.f}, nrm1 = (f32x4){0.f,0.f,0.f,0.f};   \
    _Pragma("unroll")                                                          \
    for (int kb = 0; kb < 12; ++kb) {                                          \
        unsigned ka = ((unsigned)(kb * 64) + kq16) ^ key;                      \
        bf16x8 b0 = *(const bf16x8*)(smem + abase + ka);                       \
        bf16x8 b1 = *(const bf16x8*)(smem + abase + 12288u + ka);              \
        bf16x8 aq = *(const bf16x8*)&qreg[kb];                                 \
        acc0 = __builtin_amdgcn_mfma_f32_16x16x32_bf16(aq, b0, acc0, 0, 0, 0); \
        nrm0 = __builtin_amdgcn_mfma_f32_16x16x32_bf16(b0, b0, nrm0, 0, 0, 0); \
        acc1 = __builtin_amdgcn_mfma_f32_16x16x32_bf16(aq, b1, acc1, 0, 0, 0); \
        nrm1 = __builtin_amdgcn_mfma_f32_16x16x32_bf16(b1, b1, nrm1, 0, 0, 0); \
    }                                                                          \
    if ((l >> 4) == (lb15 >> 2)) {                                             \
        float n0 = (l & 2) ? ((l & 1) ? nrm0[3] : nrm0[2])                     \
                           : ((l & 1) ? nrm0[1] : nrm0[0]);                    \
        float n1 = (l & 2) ? ((l & 1) ? nrm1[3] : nrm1[2])                     \
                           : ((l & 1) ? nrm1[1] : nrm1[0]);                    \
        RN[lb15] = n0; RN[16 + lb15] = n1;                                     \
    }                                                                          \
    asm volatile("s_waitcnt lgkmcnt(0)" ::: "memory");                         \
    __builtin_amdgcn_s_barrier();                                              \
    {                                                                          \
        float rn0 = 1.0f / (sqrtf(RN[lb15]) + EPSN);                           \
        float rn1 = 1.0f / (sqrtf(RN[16 + lb15]) + EPSN);                      \
        int row0 = w * 16 + (l >> 4) * 4;                                      \
        _Pragma("unroll")                                                      \
        for (int jj = 0; jj < 4; ++jj) {                                       \
            S[(row0 + jj) * 33 + lb15] = acc0[jj] * rn0;                       \
            S[(row0 + jj) * 33 + 16 + lb15] = acc1[jj] * rn1;                  \
        }                                                                      \
    }                                                                          \
    asm volatile("s_waitcnt lgkmcnt(0)" ::: "memory");                         \
    __builtin_amdgcn_s_barrier();                                              \
    _Pragma("unroll")                                                          \
    for (int ii = 0; ii < 8; ++ii) {                                           \
        int dl = w * 8 + ((ii + sq_) & 7);                                     \
        float sc = S[sq_ * 33 + dl];                                           \
        INS8(sc, d0 + (J) * 32 + dl);                                          \
    }                                                                          \
}

    KITER(0, 0) KITER(1, 0) KITER(2, 0) KITER(3, 1)
#undef KITER
#undef CONV

    asm volatile("s_waitcnt lgkmcnt(0)" ::: "memory");
    __builtin_amdgcn_s_barrier();
    float* Ls = (float*)smem;
    int*   Li = (int*)(smem + 8192);
#pragma unroll
    for (int r = 0; r < 8; ++r) {
        Ls[(w * 64 + sq_) * 8 + r] = ts[r];
        Li[(w * 64 + sq_) * 8 + r] = ti[r];
    }
    asm volatile("s_waitcnt lgkmcnt(0)" ::: "memory");
    __builtin_amdgcn_s_barrier();
    if (tid < 64) {
#pragma unroll
        for (int r = 0; r < 8; ++r) { ts[r] = -3.402823466e38f; ti[r] = 0x7fffffff; }
        for (int a = 0; a < 4; ++a) {
#pragma unroll
            for (int r = 0; r < 8; ++r) {
                float s2 = Ls[(a * 64 + tid) * 8 + r];
                int i2 = Li[(a * 64 + tid) * 8 + r];
                INS8(s2, i2);
            }
        }
        size_t o = ((size_t)tid * NBLK + blockIdx.x) * TOPK;
        *(float4*)&pscore[o]     = make_float4(ts[0], ts[1], ts[2], ts[3]);
        *(float4*)&pscore[o + 4] = make_float4(ts[4], ts[5], ts[6], ts[7]);
        *(int4*)&pidx[o]     = make_int4(ti[0], ti[1], ti[2], ti[3]);
        *(int4*)&pidx[o + 4] = make_int4(ti[4], ti[5], ti[6], ti[7]);
    }
}

// ---------------- K2: candidate merge (1024 blocks, parallel) ----------------
// block (q, c): merge lists c*128..c*128+127 -> top-16 -> ci[q][c][16]
__global__ __launch_bounds__(128) void cand_kernel(
        const float* __restrict__ pscore, const int* __restrict__ pidx,
        int* __restrict__ ci) {
    const int q = blockIdx.x >> 4;
    const int c = blockIdx.x & 15;
    const int tid = threadIdx.x;   // 128
    __shared__ float ls[1024];
    __shared__ int   li[1024];
    __shared__ float ls2[256];
    __shared__ int   li2[256];

    {   // L0: thread t loads its sorted 8-list (32B x2, coalesced)
        size_t o = (size_t)q * 16384 + (size_t)(c * 128 + tid) * 8;
        float4 s0 = *(const float4*)&pscore[o];
        float4 s1 = *(const float4*)&pscore[o + 4];
        int4 i0 = *(const int4*)&pidx[o];
        int4 i1 = *(const int4*)&pidx[o + 4];
        ls[tid * 8 + 0] = s0.x; ls[tid * 8 + 1] = s0.y;
        ls[tid * 8 + 2] = s0.z; ls[tid * 8 + 3] = s0.w;
        ls[tid * 8 + 4] = s1.x; ls[tid * 8 + 5] = s1.y;
        ls[tid * 8 + 6] = s1.z; ls[tid * 8 + 7] = s1.w;
        li[tid * 8 + 0] = i0.x; li[tid * 8 + 1] = i0.y;
        li[tid * 8 + 2] = i0.z; li[tid * 8 + 3] = i0.w;
        li[tid * 8 + 4] = i1.x; li[tid * 8 + 5] = i1.y;
        li[tid * 8 + 6] = i1.z; li[tid * 8 + 7] = i1.w;
    }
    __syncthreads();

    float ts[16]; int ti[16];
    if (tid < 16) {   // L1: 16 threads x 64 entries -> top-16 each
#pragma unroll
        for (int r = 0; r < 16; ++r) { ts[r] = -3.402823466e38f; ti[r] = 0x7fffffff; }
        for (int e = 0; e < 64; ++e) {
            int k = tid + e * 16;
            float s = ls[k]; int gi = li[k];
            INS16(s, gi);
        }
#pragma unroll
        for (int r = 0; r < 16; ++r) { ls2[tid * 16 + r] = ts[r]; li2[tid * 16 + r] = ti[r]; }
    }
    __syncthreads();
    if (tid == 0) {   // L2: merge 16 sorted lists (skip dominated)
#pragma unroll
        for (int r = 0; r < 16; ++r) { ts[r] = -3.402823466e38f; ti[r] = 0x7fffffff; }
        for (int t2 = 0; t2 < 16; ++t2) {
            int b = t2 * 16;
            if (ls2[b] < ts[15]) continue;
            for (int r2 = 0; r2 < 16; ++r2) {
                float s = ls2[b + r2]; int gi = li2[b + r2];
                INS16(s, gi);
            }
        }
#pragma unroll
        for (int r = 0; r < 16; ++r) ci[(q * 16 + c) * 16 + r] = ti[r];
    }
}

// ---------------- K3: parallel exact rescore (512 blocks) ----------------
__global__ __launch_bounds__(256) void rescore_kernel(
        const float* __restrict__ docs, const float* __restrict__ qn,
        const int* __restrict__ ci, float* __restrict__ cs2,
        float* __restrict__ cn2) {
    const int q = blockIdx.x >> 3;
    const int g = blockIdx.x & 7;
    const int tid = threadIdx.x;
    const int l = tid & 63, wv = tid >> 6;

    float qr[6];
#pragma unroll
    for (int i = 0; i < 6; ++i) qr[i] = qn[q * EMBED + l + 64 * i];

#pragma unroll
    for (int cc = 0; cc < 8; ++cc) {
        int cd = g * 32 + wv * 8 + cc;
        int id = ci[q * 256 + cd];
        const float* dp = docs + (size_t)id * EMBED;
        float dot = 0.f, ss = 0.f;
#pragma unroll
        for (int i = 0; i < 6; ++i) {
            float v = dp[l + 64 * i];
            dot = fmaf(v, qr[i], dot);
            ss = fmaf(v, v, ss);
        }
#pragma unroll
        for (int off = 32; off > 0; off >>= 1) {
            dot += __shfl_xor(dot, off);
            ss  += __shfl_xor(ss, off);
        }
        if (l == 0) {
            float rn = 1.0f / (sqrtf(ss) + EPSN);
            cs2[q * 256 + cd] = dot * rn;
            cn2[q * 256 + cd] = rn;
        }
    }
}

// ---------------- K4: finalize (top-8, softmax, fuse) ----------------
__global__ __launch_bounds__(256) void final_kernel(
        const float* __restrict__ docs, const int* __restrict__ ci,
        const float* __restrict__ cs2, const float* __restrict__ cn2,
        float* __restrict__ out) {
    const int q = blockIdx.x;
    const int tid = threadIdx.x;
    __shared__ int   fi[TOPK];
    __shared__ float wr[TOPK];

    if (tid == 0) {
        float ts[8]; int ti[8]; int tp[8];
#pragma unroll
        for (int r = 0; r < 8; ++r) { ts[r] = -3.402823466e38f; ti[r] = 0x7fffffff; tp[r] = 0; }
        for (int e = 0; e < 256; ++e) {
            float s = cs2[q * 256 + e]; int id = ci[q * 256 + e];
            if (s > ts[7] || (s == ts[7] && id < ti[7])) {
                ts[7] = s; ti[7] = id; tp[7] = e;
#pragma unroll
                for (int r = 7; r > 0; --r) {
                    bool sw = (ts[r] > ts[r-1]) || (ts[r] == ts[r-1] && ti[r] < ti[r-1]);
                    float a = ts[r-1]; int b = ti[r-1]; int p = tp[r-1];
                    ts[r-1] = sw ? ts[r] : a;  ti[r-1] = sw ? ti[r] : b;  tp[r-1] = sw ? tp[r] : p;
                    ts[r]   = sw ? a : ts[r];  ti[r]   = sw ? b : ti[r];  tp[r]   = sw ? p : tp[r];
                }
            }
        }
        float m = ts[0];
        float wv[8]; float sum = 0.f;
#pragma unroll
        for (int r = 0; r < 8; ++r) { wv[r] = expf(ts[r] - m); sum += wv[r]; }
        float rs = 1.0f / sum;
#pragma unroll
        for (int r = 0; r < 8; ++r) {
            fi[r] = ti[r];
            wr[r] = wv[r] * rs * cn2[q * 256 + tp[r]];
            out[BATCH * EMBED + q * TOPK + r] = ts[r];
            out[BATCH * EMBED + BATCH * TOPK + q * TOPK + r] = (float)ti[r];
        }
    }
    __syncthreads();

    for (int dim = tid; dim < EMBED; dim += 256) {
        float a = 0.f;
#pragma unroll
        for (int r = 0; r < 8; ++r)
            a += wr[r] * docs[(size_t)fi[r] * EMBED + dim];
        out[q * EMBED + dim] = a;
    }
}

// ---------------- K5: read-BW probe (fill/m13 idiom) ----------------
__global__ __launch_bounds__(256) void probe_kernel(
        const float4* __restrict__ p, float* __restrict__ o, int n4) {
    float s = 0.f;
    for (int i = blockIdx.x * 256 + threadIdx.x; i < n4; i += 2048 * 256) {
        float4 v = p[i];
        s += v.x + v.y + v.z + v.w;
    }
#pragma unroll
    for (int off = 32; off > 0; off >>= 1) s += __shfl_xor(s, off);
    if ((threadIdx.x & 63) == 0)
        o[blockIdx.x * 4 + (threadIdx.x >> 6)] = s;
}

extern "C" void kernel_launch(void* const* d_in, const int* in_sizes, int n_in,
                              void* d_out, int out_size, void* d_ws, size_t ws_size,
                              hipStream_t stream) {
    const float* query = (const float*)d_in[0];
    const float* docs  = (const float*)d_in[1];
    float* out = (float*)d_out;

    char* ws = (char*)d_ws;
    unsigned short* qhf = (unsigned short*)ws;                  // 48 KiB
    float* qn  = (float*)(ws + 49152);                          // 96 KiB
    float* pscore = (float*)(ws + 147456);                      // 4 MiB
    int*   pidx   = (int*)(ws + 147456 + 4194304ull);           // 4 MiB
    char*  b2 = ws + 147456 + 8388608ull;
    int*   ci  = (int*)b2;                                      // 64 KiB
    float* cs2 = (float*)(b2 + 65536);                          // 64 KiB
    float* cn2 = (float*)(b2 + 131072);                         // 64 KiB
    float* pr  = (float*)(b2 + 196608);                         // 32 KiB

    qprep_kernel<<<64, 64, 0, stream>>>(query, qn, qhf);
    score_topk_kernel<<<NBLK, 256, 0, stream>>>(docs, qhf, pscore, pidx);
    cand_kernel<<<BATCH * 16, 128, 0, stream>>>(pscore, pidx, ci);
    rescore_kernel<<<BATCH * 8, 256, 0, stream>>>(docs, qn, ci, cs2, cn2);
    final_kernel<<<BATCH, 256, 0, stream>>>(docs, ci, cs2, cn2, out);
    probe_kernel<<<2048, 256, 0, stream>>>((const float4*)docs, pr,
                                           NDOCS * EMBED / 4);
}

// Round 15
// 318.043 us; speedup vs baseline: 1.2150x; 1.2150x over previous
//
#include <hip/hip_runtime.h>
#include <math.h>

// NanoRAG: cosine-sim retrieval + top-8 + softmax fusion.
// K0 qprep: normalize queries -> qn fp32 + A-fragment bf16 (R10-12 proven)
// K1 score: fused hi-only MFMA + per-block top-8 (R11/R12-proven body) with
//   GRANULE-INTERLEAVED SLAB ORDER: tile J of block b reads contiguous
//   48-KB slab (J*2048+b) [R12: b*4+J]. Concurrent blocks therefore read
//   interleaved granules of ONE contiguous 100-MB quarter (marching window)
//   instead of 2048 private 192-KB regions. Only base+index change.
// K2 cand: 1024 blocks (q,chunk): merge 128 sorted lists -> top-16/chunk
// K3 rescore: 512 blocks: exact fp32 rescore of 256 candidates/query
// K4 final: top-8 of rescored, softmax, gather+fuse -> d_out
//
// d_out layout (fp32): fused[64*384], scores[64*8], idx[64*8]

#define EMBED 384
#define NDOCS 262144
#define BATCH 64
#define TOPK 8
#define NBLK 2048
#define EPSN 1e-8f

typedef __attribute__((ext_vector_type(8))) short bf16x8;
typedef __attribute__((ext_vector_type(4))) float f32x4;

#define INS8(s_, i_) do {                                                     \
    if ((s_) > ts[7] || ((s_) == ts[7] && (i_) < ti[7])) {                    \
        ts[7] = (s_); ti[7] = (i_);                                           \
        _Pragma("unroll")                                                     \
        for (int r_ = 7; r_ > 0; --r_) {                                      \
            bool sw_ = (ts[r_] > ts[r_-1]) ||                                 \
                       (ts[r_] == ts[r_-1] && ti[r_] < ti[r_-1]);             \
            float a_ = ts[r_-1]; int b_ = ti[r_-1];                           \
            ts[r_-1] = sw_ ? ts[r_] : a_;  ti[r_-1] = sw_ ? ti[r_] : b_;      \
            ts[r_]   = sw_ ? a_ : ts[r_];  ti[r_]   = sw_ ? b_ : ti[r_];      \
        }                                                                     \
    }                                                                         \
} while (0)

#define INS16(s_, i_) do {                                                    \
    if ((s_) > ts[15] || ((s_) == ts[15] && (i_) < ti[15])) {                 \
        ts[15] = (s_); ti[15] = (i_);                                         \
        _Pragma("unroll")                                                     \
        for (int r_ = 15; r_ > 0; --r_) {                                     \
            bool sw_ = (ts[r_] > ts[r_-1]) ||                                 \
                       (ts[r_] == ts[r_-1] && ti[r_] < ti[r_-1]);             \
            float a_ = ts[r_-1]; int b_ = ti[r_-1];                           \
            ts[r_-1] = sw_ ? ts[r_] : a_;  ti[r_-1] = sw_ ? ti[r_] : b_;      \
            ts[r_]   = sw_ ? a_ : ts[r_];  ti[r_]   = sw_ ? b_ : ti[r_];      \
        }                                                                     \
    }                                                                         \
} while (0)

// RNE fp32 -> bf16 (manual; proven numerics R2-R12; never cvt_pk — R4 flip)
__device__ __forceinline__ unsigned rne1(float f) {
    unsigned u = __float_as_uint(f);
    return (u + 0x7fffu + ((u >> 16) & 1u)) >> 16;
}

template<int OFF>
__device__ __forceinline__ int4 gload_s(unsigned voff, const void* sbase) {
    int4 r;
    asm volatile("global_load_dwordx4 %0, %1, %2 offset:%3"
                 : "=v"(r) : "v"(voff), "s"(sbase), "i"(OFF) : "memory");
    return r;
}

// ---------------- K0: query prep (R10-12 proven) ----------------
__global__ void qprep_kernel(const float* __restrict__ q,
                             float* __restrict__ qn,
                             unsigned short* __restrict__ qhf) {
    const int row = blockIdx.x;
    const int lane = threadIdx.x;
    float v[6];
    float s = 0.f;
#pragma unroll
    for (int i = 0; i < 6; ++i) {
        v[i] = q[row * EMBED + lane + 64 * i];
        s = fmaf(v[i], v[i], s);
    }
#pragma unroll
    for (int off = 32; off > 0; off >>= 1) s += __shfl_xor(s, off);
    float rinv = 1.0f / (sqrtf(s) + EPSN);
#pragma unroll
    for (int i = 0; i < 6; ++i) {
        int k = lane + 64 * i;
        float f = v[i] * rinv;
        qn[row * EMBED + k] = f;
        qhf[(row >> 4) * 6144 + (k >> 5) * 512 + ((k >> 3) & 3) * 128
            + (row & 15) * 8 + (k & 7)] = (unsigned short)rne1(f);
    }
}

// ---------------- K1: fused score + top-8 (granule-interleaved) ----------
__global__ __launch_bounds__(256, 3) void score_topk_kernel(
        const float* __restrict__ docs,
        const unsigned short* __restrict__ qhf,
        float* __restrict__ pscore, int* __restrict__ pidx) {
    __shared__ __align__(16) char smem[33168];
    float* S  = (float*)(smem + 24576);
    float* RN = (float*)(smem + 33024);

    const int tid = threadIdx.x;
    const int l = tid & 63;
    const int w = tid >> 6;
    const int lb15 = l & 15;
    const int bid = (int)blockIdx.x;

    int4 qreg[12];
    {
        const unsigned qvb = (unsigned)(w * 12288 + l * 16);
#pragma unroll
        for (int kb = 0; kb < 12; ++kb)
            qreg[kb] = gload_s<0>(qvb + kb * 1024u, qhf);
    }

    // tile J slab base: slab (J*2048 + bid) * 48KB; within-tile addressing
    // (vb + i*4096) is byte-identical to R12's proven pattern.
    const unsigned vb = (unsigned)(tid * 16);
    int4 rawA[6], rawB[6];
#pragma unroll
    for (int i = 0; i < 6; ++i)
        rawA[i] = gload_s<0>((unsigned)(0 * 2048 + bid) * 49152u + vb + i * 4096u, docs);
#pragma unroll
    for (int i = 0; i < 6; ++i)
        rawB[i] = gload_s<0>((unsigned)(0 * 2048 + bid) * 49152u + vb + (i + 6) * 4096u, docs);

    uint2 sh[12];
    unsigned dsw[12];
    float ts[8]; int ti[8];
#pragma unroll
    for (int r = 0; r < 8; ++r) { ts[r] = -3.402823466e38f; ti[r] = 0x7fffffff; }

    const unsigned abase = (unsigned)(lb15 * 768);
    const unsigned key = (unsigned)((l & 7) << 4);
    const unsigned kq16 = (unsigned)((l >> 4) * 16);
    const int sq_ = tid & 63;

#define CONV(i, R, ri) {                                                       \
    int F = tid + (i) * 256;                                                   \
    float f0 = __int_as_float(R[ri].x), f1 = __int_as_float(R[ri].y);          \
    float f2 = __int_as_float(R[ri].z), f3 = __int_as_float(R[ri].w);          \
    sh[i].x = rne1(f0) | (rne1(f1) << 16);                                     \
    sh[i].y = rne1(f2) | (rne1(f3) << 16);                                     \
    int dd = (F * 10923) >> 20;                                                \
    int r4 = F - dd * 96;                                                      \
    dsw[i] = (unsigned)(dd * 768) + (((unsigned)(r4 * 8)) ^ ((unsigned)((dd & 7) << 4))); \
}

#define KITER(J, LAST) {                                                       \
    asm volatile("s_waitcnt vmcnt(6)" ::: "memory");                           \
    __builtin_amdgcn_sched_barrier(0);                                         \
    _Pragma("unroll")                                                          \
    for (int i = 0; i < 6; ++i) CONV(i, rawA, i);                              \
    if (!(LAST)) {                                                             \
        _Pragma("unroll")                                                      \
        for (int i = 0; i < 6; ++i)                                            \
            rawA[i] = gload_s<0>((unsigned)((((J) + 1) * 2048 + bid)) * 49152u \
                                 + vb + i * 4096u, docs);                      \
    }                                                                          \
    asm volatile("s_waitcnt vmcnt(%0)" :: "i"((LAST) ? 0 : 6) : "memory");     \
    __builtin_amdgcn_sched_barrier(0);                                         \
    _Pragma("unroll")                                                          \
    for (int i = 6; i < 12; ++i) CONV(i, rawB, i - 6);                         \
    if (!(LAST)) {                                                             \
        _Pragma("unroll")                                                      \
        for (int i = 0; i < 6; ++i)                                            \
            rawB[i] = gload_s<0>((unsigned)((((J) + 1) * 2048 + bid)) * 49152u \
                                 + vb + (i + 6) * 4096u, docs);                \
    }                                                                          \
    asm volatile("s_waitcnt lgkmcnt(0)" ::: "memory");                         \
    __builtin_amdgcn_s_barrier();                                              \
    _Pragma("unroll")                                                          \
    for (int i = 0; i < 12; ++i) *(uint2*)(smem + dsw[i]) = sh[i];             \
    asm volatile("s_waitcnt lgkmcnt(0)" ::: "memory");                         \
    __builtin_amdgcn_s_barrier();                                              \
    f32x4 acc0 = (f32x4){0.f,0.f,0.f,0.f}, acc1 = (f32x4){0.f,0.f,0.f,0.f};   \
    f32x4 nrm0 = (f32x4){0.f,0.f,0.f,0.f}, nrm1 = (f32x4){0.f,0.f,0.f,0.f};   \
    _Pragma("unroll")                                                          \
    for (int kb = 0; kb < 12; ++kb) {                                          \
        unsigned ka = ((unsigned)(kb * 64) + kq16) ^ key;                      \
        bf16x8 b0 = *(const bf16x8*)(smem + abase + ka);                       \
        bf16x8 b1 = *(const bf16x8*)(smem + abase + 12288u + ka);              \
        bf16x8 aq = *(const bf16x8*)&qreg[kb];                                 \
        acc0 = __builtin_amdgcn_mfma_f32_16x16x32_bf16(aq, b0, acc0, 0, 0, 0); \
        nrm0 = __builtin_amdgcn_mfma_f32_16x16x32_bf16(b0, b0, nrm0, 0, 0, 0); \
        acc1 = __builtin_amdgcn_mfma_f32_16x16x32_bf16(aq, b1, acc1, 0, 0, 0); \
        nrm1 = __builtin_amdgcn_mfma_f32_16x16x32_bf16(b1, b1, nrm1, 0, 0, 0); \
    }                                                                          \
    if ((l >> 4) == (lb15 >> 2)) {                                             \
        float n0 = (l & 2) ? ((l & 1) ? nrm0[3] : nrm0[2])                     \
                           : ((l & 1) ? nrm0[1] : nrm0[0]);                    \
        float n1 = (l & 2) ? ((l & 1) ? nrm1[3] : nrm1[2])                     \
                           : ((l & 1) ? nrm1[1] : nrm1[0]);                    \
        RN[lb15] = n0; RN[16 + lb15] = n1;                                     \
    }                                                                          \
    asm volatile("s_waitcnt lgkmcnt(0)" ::: "memory");                         \
    __builtin_amdgcn_s_barrier();                                              \
    {                                                                          \
        float rn0 = 1.0f / (sqrtf(RN[lb15]) + EPSN);                           \
        float rn1 = 1.0f / (sqrtf(RN[16 + lb15]) + EPSN);                      \
        int row0 = w * 16 + (l >> 4) * 4;                                      \
        _Pragma("unroll")                                                      \
        for (int jj = 0; jj < 4; ++jj) {                                       \
            S[(row0 + jj) * 33 + lb15] = acc0[jj] * rn0;                       \
            S[(row0 + jj) * 33 + 16 + lb15] = acc1[jj] * rn1;                  \
        }                                                                      \
    }                                                                          \
    asm volatile("s_waitcnt lgkmcnt(0)" ::: "memory");                         \
    __builtin_amdgcn_s_barrier();                                              \
    _Pragma("unroll")                                                          \
    for (int ii = 0; ii < 8; ++ii) {                                           \
        int dl = w * 8 + ((ii + sq_) & 7);                                     \
        float sc = S[sq_ * 33 + dl];                                           \
        INS8(sc, ((J) * 2048 + bid) * 32 + dl);                                \
    }                                                                          \
}

    KITER(0, 0) KITER(1, 0) KITER(2, 0) KITER(3, 1)
#undef KITER
#undef CONV

    asm volatile("s_waitcnt lgkmcnt(0)" ::: "memory");
    __builtin_amdgcn_s_barrier();
    float* Ls = (float*)smem;
    int*   Li = (int*)(smem + 8192);
#pragma unroll
    for (int r = 0; r < 8; ++r) {
        Ls[(w * 64 + sq_) * 8 + r] = ts[r];
        Li[(w * 64 + sq_) * 8 + r] = ti[r];
    }
    asm volatile("s_waitcnt lgkmcnt(0)" ::: "memory");
    __builtin_amdgcn_s_barrier();
    if (tid < 64) {
#pragma unroll
        for (int r = 0; r < 8; ++r) { ts[r] = -3.402823466e38f; ti[r] = 0x7fffffff; }
        for (int a = 0; a < 4; ++a) {
#pragma unroll
            for (int r = 0; r < 8; ++r) {
                float s2 = Ls[(a * 64 + tid) * 8 + r];
                int i2 = Li[(a * 64 + tid) * 8 + r];
                INS8(s2, i2);
            }
        }
        size_t o = ((size_t)tid * NBLK + blockIdx.x) * TOPK;
        *(float4*)&pscore[o]     = make_float4(ts[0], ts[1], ts[2], ts[3]);
        *(float4*)&pscore[o + 4] = make_float4(ts[4], ts[5], ts[6], ts[7]);
        *(int4*)&pidx[o]     = make_int4(ti[0], ti[1], ti[2], ti[3]);
        *(int4*)&pidx[o + 4] = make_int4(ti[4], ti[5], ti[6], ti[7]);
    }
}

// ---------------- K2: candidate merge (1024 blocks, R12-proven) ----------
__global__ __launch_bounds__(128) void cand_kernel(
        const float* __restrict__ pscore, const int* __restrict__ pidx,
        int* __restrict__ ci) {
    const int q = blockIdx.x >> 4;
    const int c = blockIdx.x & 15;
    const int tid = threadIdx.x;   // 128
    __shared__ float ls[1024];
    __shared__ int   li[1024];
    __shared__ float ls2[256];
    __shared__ int   li2[256];

    {
        size_t o = (size_t)q * 16384 + (size_t)(c * 128 + tid) * 8;
        float4 s0 = *(const float4*)&pscore[o];
        float4 s1 = *(const float4*)&pscore[o + 4];
        int4 i0 = *(const int4*)&pidx[o];
        int4 i1 = *(const int4*)&pidx[o + 4];
        ls[tid * 8 + 0] = s0.x; ls[tid * 8 + 1] = s0.y;
        ls[tid * 8 + 2] = s0.z; ls[tid * 8 + 3] = s0.w;
        ls[tid * 8 + 4] = s1.x; ls[tid * 8 + 5] = s1.y;
        ls[tid * 8 + 6] = s1.z; ls[tid * 8 + 7] = s1.w;
        li[tid * 8 + 0] = i0.x; li[tid * 8 + 1] = i0.y;
        li[tid * 8 + 2] = i0.z; li[tid * 8 + 3] = i0.w;
        li[tid * 8 + 4] = i1.x; li[tid * 8 + 5] = i1.y;
        li[tid * 8 + 6] = i1.z; li[tid * 8 + 7] = i1.w;
    }
    __syncthreads();

    float ts[16]; int ti[16];
    if (tid < 16) {
#pragma unroll
        for (int r = 0; r < 16; ++r) { ts[r] = -3.402823466e38f; ti[r] = 0x7fffffff; }
        for (int e = 0; e < 64; ++e) {
            int k = tid + e * 16;
            float s = ls[k]; int gi = li[k];
            INS16(s, gi);
        }
#pragma unroll
        for (int r = 0; r < 16; ++r) { ls2[tid * 16 + r] = ts[r]; li2[tid * 16 + r] = ti[r]; }
    }
    __syncthreads();
    if (tid == 0) {
#pragma unroll
        for (int r = 0; r < 16; ++r) { ts[r] = -3.402823466e38f; ti[r] = 0x7fffffff; }
        for (int t2 = 0; t2 < 16; ++t2) {
            int b = t2 * 16;
            if (ls2[b] < ts[15]) continue;
            for (int r2 = 0; r2 < 16; ++r2) {
                float s = ls2[b + r2]; int gi = li2[b + r2];
                INS16(s, gi);
            }
        }
#pragma unroll
        for (int r = 0; r < 16; ++r) ci[(q * 16 + c) * 16 + r] = ti[r];
    }
}

// ---------------- K3: parallel exact rescore (512 blocks, R12-proven) -----
__global__ __launch_bounds__(256) void rescore_kernel(
        const float* __restrict__ docs, const float* __restrict__ qn,
        const int* __restrict__ ci, float* __restrict__ cs2,
        float* __restrict__ cn2) {
    const int q = blockIdx.x >> 3;
    const int g = blockIdx.x & 7;
    const int tid = threadIdx.x;
    const int l = tid & 63, wv = tid >> 6;

    float qr[6];
#pragma unroll
    for (int i = 0; i < 6; ++i) qr[i] = qn[q * EMBED + l + 64 * i];

#pragma unroll
    for (int cc = 0; cc < 8; ++cc) {
        int cd = g * 32 + wv * 8 + cc;
        int id = ci[q * 256 + cd];
        const float* dp = docs + (size_t)id * EMBED;
        float dot = 0.f, ss = 0.f;
#pragma unroll
        for (int i = 0; i < 6; ++i) {
            float v = dp[l + 64 * i];
            dot = fmaf(v, qr[i], dot);
            ss = fmaf(v, v, ss);
        }
#pragma unroll
        for (int off = 32; off > 0; off >>= 1) {
            dot += __shfl_xor(dot, off);
            ss  += __shfl_xor(ss, off);
        }
        if (l == 0) {
            float rn = 1.0f / (sqrtf(ss) + EPSN);
            cs2[q * 256 + cd] = dot * rn;
            cn2[q * 256 + cd] = rn;
        }
    }
}

// ---------------- K4: finalize (top-8, softmax, fuse; R12-proven) ---------
__global__ __launch_bounds__(256) void final_kernel(
        const float* __restrict__ docs, const int* __restrict__ ci,
        const float* __restrict__ cs2, const float* __restrict__ cn2,
        float* __restrict__ out) {
    const int q = blockIdx.x;
    const int tid = threadIdx.x;
    __shared__ int   fi[TOPK];
    __shared__ float wr[TOPK];

    if (tid == 0) {
        float ts[8]; int ti[8]; int tp[8];
#pragma unroll
        for (int r = 0; r < 8; ++r) { ts[r] = -3.402823466e38f; ti[r] = 0x7fffffff; tp[r] = 0; }
        for (int e = 0; e < 256; ++e) {
            float s = cs2[q * 256 + e]; int id = ci[q * 256 + e];
            if (s > ts[7] || (s == ts[7] && id < ti[7])) {
                ts[7] = s; ti[7] = id; tp[7] = e;
#pragma unroll
                for (int r = 7; r > 0; --r) {
                    bool sw = (ts[r] > ts[r-1]) || (ts[r] == ts[r-1] && ti[r] < ti[r-1]);
                    float a = ts[r-1]; int b = ti[r-1]; int p = tp[r-1];
                    ts[r-1] = sw ? ts[r] : a;  ti[r-1] = sw ? ti[r] : b;  tp[r-1] = sw ? tp[r] : p;
                    ts[r]   = sw ? a : ts[r];  ti[r]   = sw ? b : ti[r];  tp[r]   = sw ? p : tp[r];
                }
            }
        }
        float m = ts[0];
        float wv[8]; float sum = 0.f;
#pragma unroll
        for (int r = 0; r < 8; ++r) { wv[r] = expf(ts[r] - m); sum += wv[r]; }
        float rs = 1.0f / sum;
#pragma unroll
        for (int r = 0; r < 8; ++r) {
            fi[r] = ti[r];
            wr[r] = wv[r] * rs * cn2[q * 256 + tp[r]];
            out[BATCH * EMBED + q * TOPK + r] = ts[r];
            out[BATCH * EMBED + BATCH * TOPK + q * TOPK + r] = (float)ti[r];
        }
    }
    __syncthreads();

    for (int dim = tid; dim < EMBED; dim += 256) {
        float a = 0.f;
#pragma unroll
        for (int r = 0; r < 8; ++r)
            a += wr[r] * docs[(size_t)fi[r] * EMBED + dim];
        out[q * EMBED + dim] = a;
    }
}

extern "C" void kernel_launch(void* const* d_in, const int* in_sizes, int n_in,
                              void* d_out, int out_size, void* d_ws, size_t ws_size,
                              hipStream_t stream) {
    const float* query = (const float*)d_in[0];
    const float* docs  = (const float*)d_in[1];
    float* out = (float*)d_out;

    char* ws = (char*)d_ws;
    unsigned short* qhf = (unsigned short*)ws;                  // 48 KiB
    float* qn  = (float*)(ws + 49152);                          // 96 KiB
    float* pscore = (float*)(ws + 147456);                      // 4 MiB
    int*   pidx   = (int*)(ws + 147456 + 4194304ull);           // 4 MiB
    char*  b2 = ws + 147456 + 8388608ull;
    int*   ci  = (int*)b2;                                      // 64 KiB
    float* cs2 = (float*)(b2 + 65536);                          // 64 KiB
    float* cn2 = (float*)(b2 + 131072);                         // 64 KiB

    qprep_kernel<<<64, 64, 0, stream>>>(query, qn, qhf);
    score_topk_kernel<<<NBLK, 256, 0, stream>>>(docs, qhf, pscore, pidx);
    cand_kernel<<<BATCH * 16, 128, 0, stream>>>(pscore, pidx, ci);
    rescore_kernel<<<BATCH * 8, 256, 0, stream>>>(docs, qn, ci, cs2, cn2);
    final_kernel<<<BATCH, 256, 0, stream>>>(docs, ci, cs2, cn2, out);
}